// Round 2
// baseline (184.386 us; speedup 1.0000x reference)
//
#include <hip/hip_runtime.h>
#include <hip/hip_bf16.h>

#define DEV static __device__ __forceinline__

DEV float sigm(float x) { return 1.0f / (1.0f + __expf(-x)); }

// B=2, N=256, Nh=192, D=128, R=20
// Kernel A: s_all = where(is_h, h_emb, pad(s_heavy)); x = glu(rmsnorm(s_all)) @ W_i2 + b_i2
__global__ __launch_bounds__(256) void kA(
    const float* __restrict__ s_heavy, const int* __restrict__ is_h,
    const float* __restrict__ h_emb, const float* __restrict__ norm1_w,
    const float* __restrict__ W_i1, const float* __restrict__ b_i1,
    const float* __restrict__ W_i2, const float* __restrict__ b_i2,
    float* __restrict__ s_all, float* __restrict__ x)
{
    const int bi = blockIdx.x;           // b*256 + i
    const int b = bi >> 8, i = bi & 255;
    const int t = threadIdx.x;           // 256 threads
    __shared__ float y[128];
    __shared__ float o[256];
    __shared__ float h[128];
    __shared__ float red[4];

    float s = 0.f;
    if (t < 128) {
        if (is_h[bi] != 0) s = h_emb[t];
        else if (i < 192) s = s_heavy[(b * 192 + i) * 128 + t];
        s_all[bi * 128 + t] = s;
    }
    float ss = s * s;
    #pragma unroll
    for (int off = 32; off > 0; off >>= 1) ss += __shfl_xor(ss, off, 64);
    if ((t & 63) == 0) red[t >> 6] = ss;
    __syncthreads();
    float v = (red[0] + red[1] + red[2] + red[3]) * (1.0f / 128.0f);
    float inv = rsqrtf(v + 1e-6f);
    if (t < 128) y[t] = s * inv * (1.0f + norm1_w[t]);
    __syncthreads();

    // o = y @ W_i1 + b_i1  (128 -> 256), thread t owns col t
    float acc = b_i1[t];
    #pragma unroll 8
    for (int k = 0; k < 128; ++k) acc += y[k] * W_i1[k * 256 + t];
    o[t] = acc;
    __syncthreads();
    if (t < 128) {
        float a = o[t], g = o[t + 128];
        h[t] = a * sigm(a) * sigm(g);   // silu(a) * sigmoid(g)
    }
    __syncthreads();
    // x = h @ W_i2 + b_i2 (128 -> 384)
    for (int c = t; c < 384; c += 256) {
        float a2 = b_i2[c];
        #pragma unroll 8
        for (int k = 0; k < 128; ++k) a2 += h[k] * W_i2[k * 384 + c];
        x[(long)bi * 384 + c] = a2;
    }
}

// Kernel B: fused Wij = rbf@W_filter + b; x_inter = Wij * x_j * mask; reductions over j.
// 384 threads: grp0 (t<128) -> dq sum; grp1 -> dmuR x dir; grp2 -> dmumu x v_all.
__global__ __launch_bounds__(384) void kB(
    const float* __restrict__ rbf, const float* __restrict__ dir_ij,
    const float* __restrict__ mask_ij, const float* __restrict__ v_all,
    const float* __restrict__ W_filter, const float* __restrict__ b_filter,
    const float* __restrict__ s_all, const float* __restrict__ x,
    float* __restrict__ q, float* __restrict__ mu)
{
    const int bi = blockIdx.x;
    const int b = bi >> 8, i = bi & 255;
    const int t = threadIdx.x;  // 0..383, channel c = t
    __shared__ float rbf_s[256 * 20];
    __shared__ float dir_s[256 * 3];
    __shared__ float mask_s[256];
    __shared__ float dmuR[3 * 128];

    float wf[20];
    #pragma unroll
    for (int r = 0; r < 20; ++r) wf[r] = W_filter[r * 384 + t];
    const float bfc = b_filter[t];

    const long base_r = (long)bi * (256 * 20);
    for (int idx = t; idx < 5120; idx += 384) rbf_s[idx] = rbf[base_r + idx];
    const long base_d = (long)bi * (256 * 3);
    for (int idx = t; idx < 768; idx += 384) dir_s[idx] = dir_ij[base_d + idx];
    for (int idx = t; idx < 256; idx += 384) mask_s[idx] = mask_ij[(long)bi * 256 + idx];
    __syncthreads();

    const int grp = t >> 7, d = t & 127;   // wave-uniform group
    float a0 = 0.f, a1 = 0.f, a2 = 0.f;
    const float* xb = x + (long)b * 256 * 384;
    const float* vb = v_all + (long)b * 256 * 3 * 128;
    for (int j = 0; j < 256; ++j) {
        float dot = bfc;
        #pragma unroll
        for (int r = 0; r < 20; ++r) dot += rbf_s[j * 20 + r] * wf[r];
        float val = dot * xb[j * 384 + t] * mask_s[j];
        if (grp == 0) {
            a0 += val;
        } else if (grp == 1) {
            a0 += val * dir_s[j * 3 + 0];
            a1 += val * dir_s[j * 3 + 1];
            a2 += val * dir_s[j * 3 + 2];
        } else {
            const float* vj = vb + j * 384 + d;
            a0 += val * vj[0];
            a1 += val * vj[128];
            a2 += val * vj[256];
        }
    }
    if (grp == 0) q[bi * 128 + d] = s_all[bi * 128 + d] + a0;
    if (grp == 1) { dmuR[d] = a0; dmuR[128 + d] = a1; dmuR[256 + d] = a2; }
    __syncthreads();
    if (grp == 2) {
        const float* vi = vb + i * 384 + d;
        mu[((long)bi * 3 + 0) * 128 + d] = vi[0]   + dmuR[d]       + a0;
        mu[((long)bi * 3 + 1) * 128 + d] = vi[128] + dmuR[128 + d] + a1;
        mu[((long)bi * 3 + 2) * 128 + d] = vi[256] + dmuR[256 + d] + a2;
    }
}

// Kernel C: mixing. mu_mix = mu @ W_mu; ctx = [rmsnorm(q), |mu_V|]; GLU; epilogue.
__global__ __launch_bounds__(256) void kC(
    const float* __restrict__ W_mu, const float* __restrict__ norm2_w,
    const float* __restrict__ W_m1, const float* __restrict__ b_m1,
    const float* __restrict__ W_m2, const float* __restrict__ b_m2,
    const float* __restrict__ q, const float* __restrict__ mu,
    float* __restrict__ q_out, float* __restrict__ mu_out)
{
    const int bi = blockIdx.x;
    const int b = bi >> 8, i = bi & 255;
    const int t = threadIdx.x;  // 256
    __shared__ float mu_s[384];
    __shared__ float muV[384], muW[384];
    __shared__ float ctx[256];
    __shared__ float o[256];
    __shared__ float h[128];
    __shared__ float x2s[384];
    __shared__ float red[4];

    for (int idx = t; idx < 384; idx += 256) mu_s[idx] = mu[(long)bi * 384 + idx];
    __syncthreads();

    // mu_mix col t for r=0..2 (cols 0..127 -> mu_V, 128..255 -> mu_W)
    float m0 = 0.f, m1 = 0.f, m2 = 0.f;
    #pragma unroll 8
    for (int k = 0; k < 128; ++k) {
        float w = W_mu[k * 256 + t];
        m0 += mu_s[k] * w;
        m1 += mu_s[128 + k] * w;
        m2 += mu_s[256 + k] * w;
    }
    if (t < 128) { muV[t] = m0; muV[128 + t] = m1; muV[256 + t] = m2; }
    else { int d2 = t - 128; muW[d2] = m0; muW[128 + d2] = m1; muW[256 + d2] = m2; }

    float qv = 0.f;
    if (t < 128) qv = q[bi * 128 + t];
    float ss = qv * qv;
    #pragma unroll
    for (int off = 32; off > 0; off >>= 1) ss += __shfl_xor(ss, off, 64);
    if ((t & 63) == 0) red[t >> 6] = ss;
    __syncthreads();
    float mean = (red[0] + red[1] + red[2] + red[3]) * (1.0f / 128.0f);
    if (t < 128) {
        ctx[t] = qv * rsqrtf(mean + 1e-6f) * (1.0f + norm2_w[t]);
    } else {
        int d2 = t - 128;
        ctx[t] = sqrtf(muV[d2] * muV[d2] + muV[128 + d2] * muV[128 + d2]
                       + muV[256 + d2] * muV[256 + d2] + 1e-6f);
    }
    __syncthreads();

    // o = ctx @ W_m1 + b_m1 (256 -> 256)
    float acc = b_m1[t];
    #pragma unroll 8
    for (int k = 0; k < 256; ++k) acc += ctx[k] * W_m1[k * 256 + t];
    o[t] = acc;
    __syncthreads();
    if (t < 128) { float a = o[t], g = o[t + 128]; h[t] = a * sigm(a) * sigm(g); }
    __syncthreads();
    // x2 = h @ W_m2 + b_m2 (128 -> 384)
    for (int c = t; c < 384; c += 256) {
        float a2 = b_m2[c];
        #pragma unroll 8
        for (int k = 0; k < 128; ++k) a2 += h[k] * W_m2[k * 384 + c];
        x2s[c] = a2;
    }
    __syncthreads();

    if (t < 128) {
        const int d = t;
        float vw = muV[d] * muW[d] + muV[128 + d] * muW[128 + d] + muV[256 + d] * muW[256 + d];
        if (i < 192)
            q_out[((long)b * 192 + i) * 128 + d] = qv + x2s[d] + x2s[256 + d] * vw;
        #pragma unroll
        for (int r = 0; r < 3; ++r)
            mu_out[((long)bi * 3 + r) * 128 + d] =
                mu_s[r * 128 + d] + x2s[128 + d] * muW[r * 128 + d];
    }
}

extern "C" void kernel_launch(void* const* d_in, const int* in_sizes, int n_in,
                              void* d_out, int out_size, void* d_ws, size_t ws_size,
                              hipStream_t stream) {
    (void)in_sizes; (void)n_in; (void)out_size; (void)ws_size;
    const float* s_heavy  = (const float*)d_in[0];
    const float* v_all    = (const float*)d_in[1];
    const float* rbf      = (const float*)d_in[2];
    const float* dir_ij   = (const float*)d_in[3];
    const float* mask_ij  = (const float*)d_in[4];
    const int*   is_h     = (const int*)d_in[5];
    const float* h_emb    = (const float*)d_in[6];
    const float* W_filter = (const float*)d_in[7];
    const float* b_filter = (const float*)d_in[8];
    const float* norm1_w  = (const float*)d_in[9];
    const float* W_i1     = (const float*)d_in[10];
    const float* b_i1     = (const float*)d_in[11];
    const float* W_i2     = (const float*)d_in[12];
    const float* b_i2     = (const float*)d_in[13];
    const float* norm2_w  = (const float*)d_in[14];
    const float* W_m1     = (const float*)d_in[15];
    const float* b_m1     = (const float*)d_in[16];
    const float* W_m2     = (const float*)d_in[17];
    const float* b_m2     = (const float*)d_in[18];
    const float* W_mu     = (const float*)d_in[19];

    float* ws    = (float*)d_ws;
    float* s_all = ws;               // 2*256*128       = 65536
    float* x     = ws + 65536;       // 2*256*384       = 196608
    float* q     = ws + 262144;      // 2*256*128       = 65536
    float* mu    = ws + 327680;      // 2*256*3*128     = 196608

    float* q_out  = (float*)d_out;               // (2,192,128)
    float* mu_out = q_out + 2 * 192 * 128;       // (2,256,3,128)

    kA<<<512, 256, 0, stream>>>(s_heavy, is_h, h_emb, norm1_w, W_i1, b_i1, W_i2, b_i2,
                                s_all, x);
    kB<<<512, 384, 0, stream>>>(rbf, dir_ij, mask_ij, v_all, W_filter, b_filter,
                                s_all, x, q, mu);
    kC<<<512, 256, 0, stream>>>(W_mu, norm2_w, W_m1, b_m1, W_m2, b_m2,
                                q, mu, q_out, mu_out);
}

// Round 3
// 104.089 us; speedup vs baseline: 1.7714x; 1.7714x over previous
//
#include <hip/hip_runtime.h>
#include <hip/hip_bf16.h>

#define DEV static __device__ __forceinline__

DEV float sigm(float x) { return 1.0f / (1.0f + __expf(-x)); }

// B=2, N=256, Nh=192, D=128, R=20
// Kernel A: s_all = where(is_h, h_emb, pad(s_heavy)); x = glu(rmsnorm(s_all)) @ W_i2 + b_i2
__global__ __launch_bounds__(256) void kA(
    const float* __restrict__ s_heavy, const int* __restrict__ is_h,
    const float* __restrict__ h_emb, const float* __restrict__ norm1_w,
    const float* __restrict__ W_i1, const float* __restrict__ b_i1,
    const float* __restrict__ W_i2, const float* __restrict__ b_i2,
    float* __restrict__ s_all, float* __restrict__ x)
{
    const int bi = blockIdx.x;           // b*256 + i
    const int b = bi >> 8, i = bi & 255;
    const int t = threadIdx.x;           // 256 threads
    __shared__ float y[128];
    __shared__ float o[256];
    __shared__ float h[128];
    __shared__ float red[4];

    float s = 0.f;
    if (t < 128) {
        if (is_h[bi] != 0) s = h_emb[t];
        else if (i < 192) s = s_heavy[(b * 192 + i) * 128 + t];
        s_all[bi * 128 + t] = s;
    }
    float ss = s * s;
    #pragma unroll
    for (int off = 32; off > 0; off >>= 1) ss += __shfl_xor(ss, off, 64);
    if ((t & 63) == 0) red[t >> 6] = ss;
    __syncthreads();
    float v = (red[0] + red[1] + red[2] + red[3]) * (1.0f / 128.0f);
    float inv = rsqrtf(v + 1e-6f);
    if (t < 128) y[t] = s * inv * (1.0f + norm1_w[t]);
    __syncthreads();

    // o = y @ W_i1 + b_i1  (128 -> 256), thread t owns col t
    float acc = b_i1[t];
    #pragma unroll 8
    for (int k = 0; k < 128; ++k) acc += y[k] * W_i1[k * 256 + t];
    o[t] = acc;
    __syncthreads();
    if (t < 128) {
        float a = o[t], g = o[t + 128];
        h[t] = a * sigm(a) * sigm(g);   // silu(a) * sigmoid(g)
    }
    __syncthreads();
    // x = h @ W_i2 + b_i2 (128 -> 384)
    for (int c = t; c < 384; c += 256) {
        float a2 = b_i2[c];
        #pragma unroll 8
        for (int k = 0; k < 128; ++k) a2 += h[k] * W_i2[k * 384 + c];
        x[(long)bi * 384 + c] = a2;
    }
}

// Kernel B (partial): each block handles (b,i) and a 64-wide j-slice.
// 384 threads: grp0 (t<128) -> dq; grp1 -> dmuR x dir; grp2 -> dmumu x v_all.
// grp1+grp2 partials merged via LDS; partials written to ws:
//   part[(bi*4+js)*512 + {0..128: dq, 128..512: dmu(r*128+d)}]
__global__ __launch_bounds__(384) void kB_part(
    const float* __restrict__ rbf, const float* __restrict__ dir_ij,
    const float* __restrict__ mask_ij, const float* __restrict__ v_all,
    const float* __restrict__ W_filter, const float* __restrict__ b_filter,
    const float* __restrict__ x, float* __restrict__ part)
{
    const int blk = blockIdx.x;
    const int bi = blk >> 2, js = blk & 3;
    const int b = bi >> 8;
    const int j0 = js * 64;
    const int t = threadIdx.x;  // 0..383, channel c = t
    __shared__ float rbf_s[64 * 20];
    __shared__ float dir_s[64 * 3];
    __shared__ float mask_s[64];
    __shared__ float dmu_s[3 * 128];

    float wf[20];
    #pragma unroll
    for (int r = 0; r < 20; ++r) wf[r] = W_filter[r * 384 + t];
    const float bfc = b_filter[t];

    const long base_r = (long)bi * (256 * 20) + j0 * 20;
    for (int idx = t; idx < 1280; idx += 384) rbf_s[idx] = rbf[base_r + idx];
    const long base_d = (long)bi * (256 * 3) + j0 * 3;
    if (t < 192) dir_s[t] = dir_ij[base_d + t];
    if (t < 64) mask_s[t] = mask_ij[(long)bi * 256 + j0 + t];
    __syncthreads();

    const int grp = t >> 7, d = t & 127;   // wave-uniform group
    float a0 = 0.f, a1 = 0.f, a2 = 0.f;
    const float* xp = x + (long)b * 256 * 384 + (long)j0 * 384 + t;
    const float* vp = v_all + (long)b * 256 * 3 * 128 + (long)j0 * 384 + d;
    #pragma unroll 4
    for (int jl = 0; jl < 64; ++jl) {
        float dot = bfc;
        #pragma unroll
        for (int r = 0; r < 20; ++r) dot += rbf_s[jl * 20 + r] * wf[r];
        float val = dot * xp[jl * 384] * mask_s[jl];
        if (grp == 0) {
            a0 += val;
        } else if (grp == 1) {
            a0 += val * dir_s[jl * 3 + 0];
            a1 += val * dir_s[jl * 3 + 1];
            a2 += val * dir_s[jl * 3 + 2];
        } else {
            const float* vj = vp + jl * 384;
            a0 += val * vj[0];
            a1 += val * vj[128];
            a2 += val * vj[256];
        }
    }
    float* pb = part + (long)blk * 512;
    if (grp == 0) pb[d] = a0;
    if (grp == 1) { dmu_s[d] = a0; dmu_s[128 + d] = a1; dmu_s[256 + d] = a2; }
    __syncthreads();
    if (grp == 2) {
        pb[128 + d]       = dmu_s[d]       + a0;
        pb[128 + 128 + d] = dmu_s[128 + d] + a1;
        pb[128 + 256 + d] = dmu_s[256 + d] + a2;
    }
}

// Kernel C: reduce partials -> q, mu; mixing; epilogue -> q_out, mu_out.
__global__ __launch_bounds__(256) void kC(
    const float* __restrict__ W_mu, const float* __restrict__ norm2_w,
    const float* __restrict__ W_m1, const float* __restrict__ b_m1,
    const float* __restrict__ W_m2, const float* __restrict__ b_m2,
    const float* __restrict__ s_all, const float* __restrict__ v_all,
    const float* __restrict__ part,
    float* __restrict__ q_out, float* __restrict__ mu_out)
{
    const int bi = blockIdx.x;
    const int b = bi >> 8, i = bi & 255;
    const int t = threadIdx.x;  // 256
    __shared__ float mu_s[384];
    __shared__ float muV[384], muW[384];
    __shared__ float ctx[256];
    __shared__ float o[256];
    __shared__ float h[128];
    __shared__ float x2s[384];
    __shared__ float red[4];

    const float* pb = part + (long)bi * 4 * 512;
    for (int idx = t; idx < 384; idx += 256) {
        mu_s[idx] = v_all[(long)bi * 384 + idx]
                  + pb[128 + idx] + pb[512 + 128 + idx]
                  + pb[1024 + 128 + idx] + pb[1536 + 128 + idx];
    }
    float qv = 0.f;
    if (t < 128) {
        qv = s_all[bi * 128 + t]
           + pb[t] + pb[512 + t] + pb[1024 + t] + pb[1536 + t];
    }
    __syncthreads();

    // mu_mix col t for r=0..2 (cols 0..127 -> mu_V, 128..255 -> mu_W)
    float m0 = 0.f, m1 = 0.f, m2 = 0.f;
    #pragma unroll 8
    for (int k = 0; k < 128; ++k) {
        float w = W_mu[k * 256 + t];
        m0 += mu_s[k] * w;
        m1 += mu_s[128 + k] * w;
        m2 += mu_s[256 + k] * w;
    }
    if (t < 128) { muV[t] = m0; muV[128 + t] = m1; muV[256 + t] = m2; }
    else { int d2 = t - 128; muW[d2] = m0; muW[128 + d2] = m1; muW[256 + d2] = m2; }

    float ss = qv * qv;
    #pragma unroll
    for (int off = 32; off > 0; off >>= 1) ss += __shfl_xor(ss, off, 64);
    if ((t & 63) == 0) red[t >> 6] = ss;
    __syncthreads();
    float mean = (red[0] + red[1] + red[2] + red[3]) * (1.0f / 128.0f);
    if (t < 128) {
        ctx[t] = qv * rsqrtf(mean + 1e-6f) * (1.0f + norm2_w[t]);
    } else {
        int d2 = t - 128;
        ctx[t] = sqrtf(muV[d2] * muV[d2] + muV[128 + d2] * muV[128 + d2]
                       + muV[256 + d2] * muV[256 + d2] + 1e-6f);
    }
    __syncthreads();

    // o = ctx @ W_m1 + b_m1 (256 -> 256)
    float acc = b_m1[t];
    #pragma unroll 8
    for (int k = 0; k < 256; ++k) acc += ctx[k] * W_m1[k * 256 + t];
    o[t] = acc;
    __syncthreads();
    if (t < 128) { float a = o[t], g = o[t + 128]; h[t] = a * sigm(a) * sigm(g); }
    __syncthreads();
    // x2 = h @ W_m2 + b_m2 (128 -> 384)
    for (int c = t; c < 384; c += 256) {
        float a2 = b_m2[c];
        #pragma unroll 8
        for (int k = 0; k < 128; ++k) a2 += h[k] * W_m2[k * 384 + c];
        x2s[c] = a2;
    }
    __syncthreads();

    if (t < 128) {
        const int d = t;
        float vw = muV[d] * muW[d] + muV[128 + d] * muW[128 + d] + muV[256 + d] * muW[256 + d];
        if (i < 192)
            q_out[((long)b * 192 + i) * 128 + d] = qv + x2s[d] + x2s[256 + d] * vw;
        #pragma unroll
        for (int r = 0; r < 3; ++r)
            mu_out[((long)bi * 3 + r) * 128 + d] =
                mu_s[r * 128 + d] + x2s[128 + d] * muW[r * 128 + d];
    }
}

extern "C" void kernel_launch(void* const* d_in, const int* in_sizes, int n_in,
                              void* d_out, int out_size, void* d_ws, size_t ws_size,
                              hipStream_t stream) {
    (void)in_sizes; (void)n_in; (void)out_size; (void)ws_size;
    const float* s_heavy  = (const float*)d_in[0];
    const float* v_all    = (const float*)d_in[1];
    const float* rbf      = (const float*)d_in[2];
    const float* dir_ij   = (const float*)d_in[3];
    const float* mask_ij  = (const float*)d_in[4];
    const int*   is_h     = (const int*)d_in[5];
    const float* h_emb    = (const float*)d_in[6];
    const float* W_filter = (const float*)d_in[7];
    const float* b_filter = (const float*)d_in[8];
    const float* norm1_w  = (const float*)d_in[9];
    const float* W_i1     = (const float*)d_in[10];
    const float* b_i1     = (const float*)d_in[11];
    const float* W_i2     = (const float*)d_in[12];
    const float* b_i2     = (const float*)d_in[13];
    const float* norm2_w  = (const float*)d_in[14];
    const float* W_m1     = (const float*)d_in[15];
    const float* b_m1     = (const float*)d_in[16];
    const float* W_m2     = (const float*)d_in[17];
    const float* b_m2     = (const float*)d_in[18];
    const float* W_mu     = (const float*)d_in[19];

    float* ws    = (float*)d_ws;
    float* s_all = ws;               // 2*256*128        = 65536 floats
    float* x     = ws + 65536;       // 2*256*384        = 196608 floats
    float* part  = ws + 262144;      // 2048 * 512       = 1048576 floats (4 MB)

    float* q_out  = (float*)d_out;               // (2,192,128)
    float* mu_out = q_out + 2 * 192 * 128;       // (2,256,3,128)

    kA<<<512, 256, 0, stream>>>(s_heavy, is_h, h_emb, norm1_w, W_i1, b_i1, W_i2, b_i2,
                                s_all, x);
    kB_part<<<2048, 384, 0, stream>>>(rbf, dir_ij, mask_ij, v_all, W_filter, b_filter,
                                      x, part);
    kC<<<512, 256, 0, stream>>>(W_mu, norm2_w, W_m1, b_m1, W_m2, b_m2,
                                s_all, v_all, part, q_out, mu_out);
}